// Round 10
// baseline (1046.397 us; speedup 1.0000x reference)
//
#include <hip/hip_runtime.h>
#include <stdint.h>

// Problem constants (match reference)
#define NP 32    // num networks (P)
#define NH 128   // hidden (H)
#define NB 32    // batch (B)
#define NT 256   // time (T)
#define FH 512   // 4*H

typedef __attribute__((ext_vector_type(4))) float float4_t;
typedef __attribute__((ext_vector_type(8))) __bf16 bf16x8;

static __device__ __forceinline__ float4_t mfma_bf16(bf16x8 a, bf16x8 b, float4_t c) {
  return __builtin_amdgcn_mfma_f32_16x16x32_bf16(a, b, c, 0, 0, 0);
}

#define LOG2E 1.4426950408889634f

// Raw workgroup barrier: drains LDS ops only (cross-wave h visibility), does
// NOT drain vmcnt — pending global loads/stores stay in flight across it.
#define BAR() __asm__ volatile("s_waitcnt lgkmcnt(0)\n\ts_barrier" ::: "memory")

// R10: ANTI-PHASE — 2 independent blocks per CU (M=2, 512 blocks).
// R8 post-mortem: step loop is phase-locked (VALUBusy 44%, MfmaUtil 34%,
// yet 2000 cyc/step): all waves of a block burst the same pipe at the same
// time, so no pipe overlaps another. Waves of DIFFERENT blocks drift freely
// (separate barriers) and fill each other's idle phases (m114 MFMA/VALU
// co-scheduling). Per-CU per-step issue totals are UNCHANGED vs R8 (trans
// redundancy 2x cancels 2 blocks/CU; MFMA instr/block invariant; DS same).
// The ~900 cyc/step of phase-lock exposure is what this buys back.
// CRITICAL: VGPR <= 128 for 2 blocks/CU -> __launch_bounds__(512, 4).
// SESSION RULES: no DS-pipe/cross-lane ops in loop (R5); x via register
// prefetch only (R3); 2 waves/SIMD per block (R4/R9); no deep dependent
// MFMA chains on one wave (R6).
//
// Grid: 512 blocks; net = blockIdx&31 (same-net blocks XCD-local for weight
// L2 reuse), bq = blockIdx>>5 -> batches {2bq, 2bq+1} (M=2 real rows).
// Dup trick: A rows hold batch l16&1 -> C reg r = batch r&1; lane adopts
// reg index quad&1 (1 cndmask per gate). Quads 2,3 duplicate quads 0,1
// (redundant compute, masked h-write) — instr count per wave unchanged.
__global__ __launch_bounds__(512, 4) void clstm_fused(
    const float* __restrict__ X, const float* __restrict__ Wih,
    const float* __restrict__ Whh, const float* __restrict__ bih,
    const float* __restrict__ bhh, const float* __restrict__ Wout,
    const float* __restrict__ bout, float* __restrict__ out)
{
  const int net = blockIdx.x & 31, bq = blockIdx.x >> 5;
  const int tid = threadIdx.x;
  const int w = tid >> 6, lane = tid & 63;
  const int quad = lane >> 4, l16 = lane & 15;

  // h A-fragments, double buffered, 2 DISTINCT rows: [buf][kc][kquad][m<2][j]
  __shared__ __bf16 hfrag[2][4][4][2][8];   // 1 KB total

  { // zero BOTH buffers (h0 = 0): 1KB = 256 ints, first 256 threads
    if (tid < 256) ((int*)hfrag)[tid] = 0;
  }
  __syncthreads();  // once, outside the loop

  // ---- load weights into register B-fragments (one-time) ----
  // B-frag layout for 16x16x32: lane holds B[k = quad*8 + j][n = l16].
  bf16x8 bfrag[4][5];
  float4_t bias4[4];
#pragma unroll
  for (int g = 0; g < 4; ++g) {
    const float scale = (g == 2) ? (-2.0f*LOG2E) : (-LOG2E);
    const int col = g*NH + w*16 + l16;
#pragma unroll
    for (int kc = 0; kc < 5; ++kc) {
      const float* src = (kc == 0) ? (Wih + ((size_t)net*FH + col)*NP + quad*8)
                                   : (Whh + ((size_t)net*FH + col)*NH + (kc-1)*32 + quad*8);
      bf16x8 bf;
#pragma unroll
      for (int j = 0; j < 8; ++j) bf[j] = (__bf16)(src[j] * scale);
      bfrag[g][kc] = bf;
    }
    const float b = (bih[net*FH + col] + bhh[net*FH + col]) * scale;
    bias4[g] = (float4_t){b, b, b, b};
  }

  // head B-frags: B[k][n] = wout[k] broadcast over all 16 cols n.
  bf16x8 wof[4];
#pragma unroll
  for (int kc = 0; kc < 4; ++kc) {
    const float* wp = Wout + net*NH + kc*32 + quad*8;
#pragma unroll
    for (int j = 0; j < 8; ++j) wof[kc][j] = (__bf16)wp[j];
  }
  const float bo = bout[net];
  const float4_t bo4 = {bo, bo, bo, bo};
  const float4_t z4  = {0.f, 0.f, 0.f, 0.f};   // loop-invariant C-root

  // c state, PRE-SCALED by -2log2e
  float cs = 0.f;
  const float S2 = -2.0f*LOG2E;
  const int mb = quad & 1;                     // this lane's batch (local)

  // x A-frag source: row l16 -> batch bq*2 + (l16&1) (8x dup)
  const float* xrow = X + (size_t)(bq*2 + (l16 & 1))*(NT*NP) + quad*8;

  // h write coords for unit u = w*16 + l16; row = mb, write iff quad < 2
  const int kcp = w >> 1, q2 = ((w & 1) << 1) | (l16 >> 3), jj = l16 & 7;
  const bool wql = quad < 2;

  // head store base: out[(bq*2 + r)*NT*NP + t*NP + net], r = 0,1 from lane 0
  float* outp = out + ((size_t)bq*2)*(NT*NP) + net;

  // preload + convert x for t=0; xp then walks t=1..NT-1
  bf16x8 ax;
  {
    float xv0[8];
    *(float4_t*)&xv0[0] = *(const float4_t*)xrow;
    *(float4_t*)&xv0[4] = *(const float4_t*)(xrow + 4);
#pragma unroll
    for (int j = 0; j < 8; ++j) ax[j] = (__bf16)xv0[j];
  }
  const float* xp = xrow + NP;
  float xv[8] = {0.f,0.f,0.f,0.f,0.f,0.f,0.f,0.f};

  for (int t = 0; t < NT; ++t) {
    const int rd = t & 1, wr = rd ^ 1;

    // ---- 1. h A-frags (row = l16&1; 8-lane same-address broadcast) ----
    bf16x8 ah[4];
#pragma unroll
    for (int kc = 0; kc < 4; ++kc)
      ah[kc] = *(const bf16x8*)&hfrag[rd][kc][quad][l16 & 1][0];

    // ---- 2. x-MFMAs first: no LDS dependence, fills ds_read latency ----
    float4_t accx[4];
#pragma unroll
    for (int g = 0; g < 4; ++g)
      accx[g] = mfma_bf16(ax, bfrag[g][0], bias4[g]);

    // ---- 3. x prefetch for t+1 (scalar-guarded, pointer-incremented) ----
    if (t + 1 < NT) {
      *(float4_t*)&xv[0] = *(const float4_t*)xp;
      *(float4_t*)&xv[4] = *(const float4_t*)(xp + 4);
    }

    // ---- 4. h-MFMAs: 4 gates, two parallel chains each (depth 2) ----
    float4_t acc[4];
#pragma unroll
    for (int g = 0; g < 4; ++g) {
      float4_t a0 = mfma_bf16(ah[0], bfrag[g][1], accx[g]);
      float4_t a1 = mfma_bf16(ah[2], bfrag[g][3], z4);
      a0 = mfma_bf16(ah[1], bfrag[g][2], a0);
      a1 = mfma_bf16(ah[3], bfrag[g][4], a1);
      acc[g] = a0 + a1;
    }

    // ---- 5. select this lane's batch (= quad&1): reg 0 or 1 ----
    float gv[4];
#pragma unroll
    for (int g = 0; g < 4; ++g)
      gv[g] = mb ? acc[g][1] : acc[g][0];

    // ---- 6. activation + state update: ONE (batch,unit) pair per lane ----
    float h;
    {
      float ei = __builtin_amdgcn_exp2f(gv[0]);
      float ig = __builtin_amdgcn_rcpf(1.0f + ei);            // sigmoid(i)
      float ef = __builtin_amdgcn_exp2f(gv[1]);
      float fg = __builtin_amdgcn_rcpf(1.0f + ef);            // sigmoid(f)
      float eg = __builtin_amdgcn_exp2f(fminf(gv[2], 126.0f));
      float rg = __builtin_amdgcn_rcpf(1.0f + eg);
      float t0 = S2 * rg;
      float gg2 = t0 - t0 * eg;                               // tanh(g)*S2
      float eo = __builtin_amdgcn_exp2f(gv[3]);
      float og = __builtin_amdgcn_rcpf(1.0f + eo);            // sigmoid(o)
      cs = fg * cs + ig * gg2;                                // c * S2
      float ec = __builtin_amdgcn_exp2f(fminf(cs, 126.0f));
      float rc = __builtin_amdgcn_rcpf(1.0f + ec);
      float th = rc - ec * rc;                                // tanh(c)
      h = og * th;
    }

    // ---- 7. write h' (bf16): 1 ds_write_b16 from quads 0,1 only ----
    if (wql) hfrag[wr][kcp][q2][mb][jj] = (__bf16)h;

    // ---- 8. fused head (wave 0; ah = h_{t-1} -> out[t-1]) ----
    if (w == 0 && t > 0) {
      float4_t p0 = mfma_bf16(ah[0], wof[0], bo4);
      float4_t p1 = mfma_bf16(ah[2], wof[2], z4);
      p0 = mfma_bf16(ah[1], wof[1], p0);
      p1 = mfma_bf16(ah[3], wof[3], p1);
      float4_t po = p0 + p1;
      if (lane == 0) {   // C rows 0,1 = batches 0,1
        outp[(t - 1)*NP] = po[0];
        outp[(size_t)(NT*NP) + (t - 1)*NP] = po[1];
      }
    }

    // ---- 9. convert next x; advance pointer ----
#pragma unroll
    for (int j = 0; j < 8; ++j) ax[j] = (__bf16)xv[j];
    xp += NP;

    BAR();  // lgkmcnt-only barrier
  }

  // ---- epilogue: head for t = NT-1 (h_{NT-1} is in hfrag[NT&1]) ----
  if (w == 0) {
    bf16x8 ahf[4];
#pragma unroll
    for (int kc = 0; kc < 4; ++kc)
      ahf[kc] = *(const bf16x8*)&hfrag[NT & 1][kc][quad][l16 & 1][0];
    float4_t p0 = mfma_bf16(ahf[0], wof[0], bo4);
    float4_t p1 = mfma_bf16(ahf[2], wof[2], z4);
    p0 = mfma_bf16(ahf[1], wof[1], p0);
    p1 = mfma_bf16(ahf[3], wof[3], p1);
    float4_t po = p0 + p1;
    if (lane == 0) {
      outp[(NT - 1)*NP] = po[0];
      outp[(size_t)(NT*NP) + (NT - 1)*NP] = po[1];
    }
  }
}

extern "C" void kernel_launch(void* const* d_in, const int* in_sizes, int n_in,
                              void* d_out, int out_size, void* d_ws, size_t ws_size,
                              hipStream_t stream) {
  const float* X    = (const float*)d_in[0];
  const float* Wih  = (const float*)d_in[1];
  const float* Whh  = (const float*)d_in[2];
  const float* bih  = (const float*)d_in[3];
  const float* bhh  = (const float*)d_in[4];
  const float* Wout = (const float*)d_in[5];
  const float* bout = (const float*)d_in[6];
  float* out = (float*)d_out;
  (void)in_sizes; (void)n_in; (void)out_size; (void)d_ws; (void)ws_size;

  clstm_fused<<<512, 512, 0, stream>>>(X, Wih, Whh, bih, bhh, Wout, bout, out);
}

// Round 11
// 363.071 us; speedup vs baseline: 2.8821x; 2.8821x over previous
//
#include <hip/hip_runtime.h>
#include <stdint.h>

// Problem constants (match reference)
#define NP 32    // num networks (P)
#define NH 128   // hidden (H)
#define NB 32    // batch (B)
#define NT 256   // time (T)
#define FH 512   // 4*H

typedef __attribute__((ext_vector_type(4))) float float4_t;
typedef __attribute__((ext_vector_type(8))) __bf16 bf16x8;

static __device__ __forceinline__ float4_t mfma_bf16(bf16x8 a, bf16x8 b, float4_t c) {
  return __builtin_amdgcn_mfma_f32_16x16x32_bf16(a, b, c, 0, 0, 0);
}

#define LOG2E 1.4426950408889634f

// Raw workgroup barrier: drains LDS ops only (cross-wave h visibility), does
// NOT drain vmcnt — pending global loads/stores stay in flight across it.
#define BAR() __asm__ volatile("s_waitcnt lgkmcnt(0)\n\ts_barrier" ::: "memory")

// R11: ANTI-PHASE, take 2 — fat waves so the register budget is LOOSE.
// R10 post-mortem: __launch_bounds__(512,4) (cap 128) made the allocator
// clamp to 64 VGPRs and spill the weight fragments to scratch (FETCH 173MB,
// WRITE 49MB, 1040us). The anti-phase thesis was never tested.
// This config: 4 fat waves/block (32 units each), cap 256 VGPRs
// (launch_bounds(256,2)); R9 measured this weight layout at 180 VGPRs ->
// ~76 regs of slack, no spill. 512 blocks (M=2) -> 2 independent barrier
// domains per CU; R9 showed ~2000 cyc/step of phase-lock exposure at 1
// block/CU for this shape — the second block's bursts fill it (m114).
// Per-CU per wall-step: trans 80 instr, DS 32 reads, VALU ~= R8; MFMA 328
// instr (~400 cyc; block-level weight duplication is the price).
// Micro: bias moved OUT of the MFMA C-root (z4 roots; bias added post-
// select as a per-lane scalar) — saves 32 VGPRs of broadcast float4s.
// SESSION RULES: no DS/cross-lane in loop (R5); x register prefetch (R3);
// no deep dependent MFMA chains (R6); never cap VGPR below usage (R10).
//
// Grid: 512 blocks; net = blockIdx&31 (co-resident blocks likely same net
// -> weight L2 reuse), bq = blockIdx>>5 -> batches {2bq, 2bq+1}.
// Lane mapping (wave w owns units [32w,32w+32)): ut_sel = quad>>1,
// mb = quad&1, unit = 32w + 16*ut_sel + l16 -> exactly 1 (batch,unit)
// pair per lane (64 = 2 batches x 32 units). A rows hold batch l16&1
// (8x dup, LDS broadcast); C reg r = batch r; select = 2 cndmask/gate.
__global__ __launch_bounds__(256, 2) void clstm_fused(
    const float* __restrict__ X, const float* __restrict__ Wih,
    const float* __restrict__ Whh, const float* __restrict__ bih,
    const float* __restrict__ bhh, const float* __restrict__ Wout,
    const float* __restrict__ bout, float* __restrict__ out)
{
  const int net = blockIdx.x & 31, bq = blockIdx.x >> 5;
  const int tid = threadIdx.x;
  const int w = tid >> 6, lane = tid & 63;
  const int quad = lane >> 4, l16 = lane & 15;
  const int ut_sel = quad >> 1, mb = quad & 1;

  // h A-fragments, double buffered, 2 DISTINCT rows: [buf][kc][kquad][m<2][j]
  __shared__ __bf16 hfrag[2][4][4][2][8];   // 1 KB total

  { // zero BOTH buffers (h0 = 0): 1KB = 256 ints, 1 per thread
    ((int*)hfrag)[tid] = 0;
  }
  __syncthreads();  // once, outside the loop

  // ---- load weights into register B-fragments (one-time) ----
  // B-frag layout for 16x16x32: lane holds B[k = quad*8 + j][n = l16].
  // ut in {0,1}: unit u = 32w + 16ut + l16; gate col = g*128 + u.
  bf16x8 bfrag[2][4][5];
#pragma unroll
  for (int ut = 0; ut < 2; ++ut) {
#pragma unroll
    for (int g = 0; g < 4; ++g) {
      const float scale = (g == 2) ? (-2.0f*LOG2E) : (-LOG2E);
      const int col = g*NH + 32*w + 16*ut + l16;
#pragma unroll
      for (int kc = 0; kc < 5; ++kc) {
        const float* src = (kc == 0) ? (Wih + ((size_t)net*FH + col)*NP + quad*8)
                                     : (Whh + ((size_t)net*FH + col)*NH + (kc-1)*32 + quad*8);
        bf16x8 bf;
#pragma unroll
        for (int j = 0; j < 8; ++j) bf[j] = (__bf16)(src[j] * scale);
        bfrag[ut][g][kc] = bf;
      }
    }
  }
  // per-lane scalar bias for THIS lane's unit (added post-select, pre-exp2)
  float bl[4];
#pragma unroll
  for (int g = 0; g < 4; ++g) {
    const float scale = (g == 2) ? (-2.0f*LOG2E) : (-LOG2E);
    const int col = g*NH + 32*w + 16*ut_sel + l16;
    bl[g] = (bih[net*FH + col] + bhh[net*FH + col]) * scale;
  }

  // head B-frags: B[k][n] = wout[k] broadcast over all 16 cols n.
  bf16x8 wof[4];
#pragma unroll
  for (int kc = 0; kc < 4; ++kc) {
    const float* wp = Wout + net*NH + kc*32 + quad*8;
#pragma unroll
    for (int j = 0; j < 8; ++j) wof[kc][j] = (__bf16)wp[j];
  }
  const float bo = bout[net];
  const float4_t bo4 = {bo, bo, bo, bo};
  const float4_t z4  = {0.f, 0.f, 0.f, 0.f};   // loop-invariant C-root

  // c state, PRE-SCALED by -2log2e
  float cs = 0.f;
  const float S2 = -2.0f*LOG2E;

  // x A-frag source: row l16 -> batch bq*2 + (l16&1) (8x dup)
  const float* xrow = X + (size_t)(bq*2 + (l16 & 1))*(NT*NP) + quad*8;

  // h write coords: unit u = 32w + 16*ut_sel + l16 -> kc = w,
  // kquad = 2*ut_sel + (l16>>3), j = l16&7, row = mb. All 64 lanes write.
  const int q2 = 2*ut_sel + (l16 >> 3), jj = l16 & 7;

  // head store base: out[(bq*2 + r)*NT*NP + t*NP + net], r = 0,1 from lane 0
  float* outp = out + ((size_t)bq*2)*(NT*NP) + net;

  // preload + convert x for t=0; xp then walks t=1..NT-1
  bf16x8 ax;
  {
    float xv0[8];
    *(float4_t*)&xv0[0] = *(const float4_t*)xrow;
    *(float4_t*)&xv0[4] = *(const float4_t*)(xrow + 4);
#pragma unroll
    for (int j = 0; j < 8; ++j) ax[j] = (__bf16)xv0[j];
  }
  const float* xp = xrow + NP;
  float xv[8] = {0.f,0.f,0.f,0.f,0.f,0.f,0.f,0.f};

  for (int t = 0; t < NT; ++t) {
    const int rd = t & 1, wr = rd ^ 1;

    // ---- 1. h A-frags (row = l16&1; 8-lane same-address broadcast) ----
    bf16x8 ah[4];
#pragma unroll
    for (int kc = 0; kc < 4; ++kc)
      ah[kc] = *(const bf16x8*)&hfrag[rd][kc][quad][l16 & 1][0];

    // ---- 2. x-MFMAs first: no LDS dependence, fills ds_read latency ----
    float4_t accx[2][4];
#pragma unroll
    for (int ut = 0; ut < 2; ++ut)
#pragma unroll
      for (int g = 0; g < 4; ++g)
        accx[ut][g] = mfma_bf16(ax, bfrag[ut][g][0], z4);

    // ---- 3. x prefetch for t+1 (scalar-guarded, pointer-incremented) ----
    if (t + 1 < NT) {
      *(float4_t*)&xv[0] = *(const float4_t*)xp;
      *(float4_t*)&xv[4] = *(const float4_t*)(xp + 4);
    }

    // ---- 4. h-MFMAs: 8 tiles x two parallel chains (depth 2) ----
    float4_t acc[2][4];
#pragma unroll
    for (int ut = 0; ut < 2; ++ut) {
#pragma unroll
      for (int g = 0; g < 4; ++g) {
        float4_t a0 = mfma_bf16(ah[0], bfrag[ut][g][1], accx[ut][g]);
        float4_t a1 = mfma_bf16(ah[2], bfrag[ut][g][3], z4);
        a0 = mfma_bf16(ah[1], bfrag[ut][g][2], a0);
        a1 = mfma_bf16(ah[3], bfrag[ut][g][4], a1);
        acc[ut][g] = a0 + a1;
      }
    }

    // ---- 5. select lane's pair (ut = quad>>1, batch = quad&1) + bias ----
    float gv[4];
#pragma unroll
    for (int g = 0; g < 4; ++g) {
      float a0 = mb ? acc[0][g][1] : acc[0][g][0];
      float a1 = mb ? acc[1][g][1] : acc[1][g][0];
      gv[g] = (ut_sel ? a1 : a0) + bl[g];
    }

    // ---- 6. activation + state update: ONE (batch,unit) pair per lane ----
    float h;
    {
      float ei = __builtin_amdgcn_exp2f(gv[0]);
      float ig = __builtin_amdgcn_rcpf(1.0f + ei);            // sigmoid(i)
      float ef = __builtin_amdgcn_exp2f(gv[1]);
      float fg = __builtin_amdgcn_rcpf(1.0f + ef);            // sigmoid(f)
      float eg = __builtin_amdgcn_exp2f(fminf(gv[2], 126.0f));
      float rg = __builtin_amdgcn_rcpf(1.0f + eg);
      float t0 = S2 * rg;
      float gg2 = t0 - t0 * eg;                               // tanh(g)*S2
      float eo = __builtin_amdgcn_exp2f(gv[3]);
      float og = __builtin_amdgcn_rcpf(1.0f + eo);            // sigmoid(o)
      cs = fg * cs + ig * gg2;                                // c * S2
      float ec = __builtin_amdgcn_exp2f(fminf(cs, 126.0f));
      float rc = __builtin_amdgcn_rcpf(1.0f + ec);
      float th = rc - ec * rc;                                // tanh(c)
      h = og * th;
    }

    // ---- 7. write h' (bf16): 1 ds_write_b16, all 64 lanes distinct ----
    hfrag[wr][w][q2][mb][jj] = (__bf16)h;

    // ---- 8. fused head (wave 0; ah = h_{t-1} -> out[t-1]) ----
    if (w == 0 && t > 0) {
      float4_t p0 = mfma_bf16(ah[0], wof[0], bo4);
      float4_t p1 = mfma_bf16(ah[2], wof[2], z4);
      p0 = mfma_bf16(ah[1], wof[1], p0);
      p1 = mfma_bf16(ah[3], wof[3], p1);
      float4_t po = p0 + p1;
      if (lane == 0) {   // C rows 0,1 = batches 0,1
        outp[(t - 1)*NP] = po[0];
        outp[(size_t)(NT*NP) + (t - 1)*NP] = po[1];
      }
    }

    // ---- 9. convert next x; advance pointer ----
#pragma unroll
    for (int j = 0; j < 8; ++j) ax[j] = (__bf16)xv[j];
    xp += NP;

    BAR();  // lgkmcnt-only barrier
  }

  // ---- epilogue: head for t = NT-1 (h_{NT-1} is in hfrag[NT&1]) ----
  if (w == 0) {
    bf16x8 ahf[4];
#pragma unroll
    for (int kc = 0; kc < 4; ++kc)
      ahf[kc] = *(const bf16x8*)&hfrag[NT & 1][kc][quad][l16 & 1][0];
    float4_t p0 = mfma_bf16(ahf[0], wof[0], bo4);
    float4_t p1 = mfma_bf16(ahf[2], wof[2], z4);
    p0 = mfma_bf16(ahf[1], wof[1], p0);
    p1 = mfma_bf16(ahf[3], wof[3], p1);
    float4_t po = p0 + p1;
    if (lane == 0) {
      outp[(NT - 1)*NP] = po[0];
      outp[(size_t)(NT*NP) + (NT - 1)*NP] = po[1];
    }
  }
}

extern "C" void kernel_launch(void* const* d_in, const int* in_sizes, int n_in,
                              void* d_out, int out_size, void* d_ws, size_t ws_size,
                              hipStream_t stream) {
  const float* X    = (const float*)d_in[0];
  const float* Wih  = (const float*)d_in[1];
  const float* Whh  = (const float*)d_in[2];
  const float* bih  = (const float*)d_in[3];
  const float* bhh  = (const float*)d_in[4];
  const float* Wout = (const float*)d_in[5];
  const float* bout = (const float*)d_in[6];
  float* out = (float*)d_out;
  (void)in_sizes; (void)n_in; (void)out_size; (void)d_ws; (void)ws_size;

  clstm_fused<<<512, 256, 0, stream>>>(X, Wih, Whh, bih, bhh, Wout, bout, out);
}